// Round 4
// baseline (567.694 us; speedup 1.0000x reference)
//
#include <hip/hip_runtime.h>

#define NL 8
#define BPL 524288
#define NB (NL * BPL)            // 4194304 buckets
#define NS 8
#define GRAV 9.8f

// 0.5*(tanh(h)+1) == 1/(1+exp(-2h)) -> sigmoid(2h) via v_exp + v_rcp.
__device__ __forceinline__ float spigot_q(float th, float hgt, float area, float Hb) {
    const float h   = fmaxf(0.0f, Hb - hgt);
    const float e   = __expf(-2.0f * h);
    const float mod = __builtin_amdgcn_rcpf(1.0f + e);
    return th * __builtin_amdgcn_sqrtf(2.0f * GRAV * h) * mod * area;
}

__device__ __forceinline__ void nt_store_f2(float* p, float2 v) {
    unsigned long long bits;
    __builtin_memcpy(&bits, &v, 8);
    __builtin_nontemporal_store(bits, reinterpret_cast<unsigned long long*>(p));
}

// ---------------------------------------------------------------------------
// One thread per SPIGOT-PAIR (4 threads/bucket, NB*4 = 16.8M threads).
// All large streams are perfectly unit-stride coalesced:
//   theta: float2 @ 8B/lane, S: float4 @ 16B/lane, s_q: float2 @ 8B/lane.
// Wave = 16 buckets, fully autonomous (no barrier on main path):
//   - bucket outflow: shfl_xor(1,2) within each 4-lane group
//   - inflow = shfl_up(of, 4); first group takes the recomputed boundary
//     outflow (lanes 0..3 recompute the wave-predecessor bucket, loads
//     HOISTED to kernel top so they overlap the main loads).
//   - s_q / H_new written NON-TEMPORALLY (never re-read; preserves L2/L3
//     residency of the input set across iterations).
//   - net_out: last-layer blocks only (8192): wave shfl -> LDS -> 1 atomic.
// d_ws untouched (ws poison fills are unconditional, ~340us fixed floor).
// ---------------------------------------------------------------------------
__global__ __launch_bounds__(256) void fused_kernel(
    const float* __restrict__ H,
    const float* __restrict__ S,
    const float* __restrict__ theta,
    const float* __restrict__ precip,
    float* __restrict__ s_q,
    float* __restrict__ H_new,
    float* __restrict__ net_out)
{
    const int t      = blockIdx.x * 256 + threadIdx.x;  // spigot-pair index
    const int lane   = threadIdx.x & 63;
    const int bucket = t >> 2;
    const int pb     = ((t - lane) >> 2) - 1;           // wave's predecessor bucket

    // ---- hoisted boundary loads: lanes 0..3 fetch bucket pb's data ----
    float2 pt = make_float2(0.0f, 0.0f);
    float4 ps = make_float4(0.0f, 0.0f, 0.0f, 0.0f);
    float  pH = 0.0f, pre = 0.0f;
    if (pb >= 0) {
        if (lane < 4) {
            pt = reinterpret_cast<const float2*>(theta)[pb * 4 + lane];
            ps = reinterpret_cast<const float4*>(S)[pb * 4 + lane];
            pH = H[pb];
        }
    } else if (lane == 0) {
        pre = precip[0];                 // bucket 0 inflow = precip
    }

    // ---- main loads: unit-stride, issued back-to-back ----
    const float  Hb = H[bucket];
    const float2 tv = reinterpret_cast<const float2*>(theta)[t];
    const float4 sv = reinterpret_cast<const float4*>(S)[t];

    // ---- 2 spigots per thread ----
    const float q0 = spigot_q(tv.x, sv.x, sv.y, Hb);
    const float q1 = spigot_q(tv.y, sv.z, sv.w, Hb);

    nt_store_f2(s_q + (size_t)t * 2, make_float2(q0, q1));

    // ---- bucket outflow: reduce over the 4-lane group ----
    float of = q0 + q1;
    of += __shfl_xor(of, 1);
    of += __shfl_xor(of, 2);             // uniform over each 4-lane group

    // ---- boundary bucket outflow (lanes 0..3; zeros elsewhere) ----
    float pq = spigot_q(pt.x, ps.x, ps.y, pH) + spigot_q(pt.y, ps.z, ps.w, pH);
    pq += __shfl_xor(pq, 1);
    pq += __shfl_xor(pq, 2);             // lanes 0..3: prev bucket's outflow

    // ---- inflow + H_new (one writer per bucket) ----
    const float prev = __shfl_up(of, 4); // valid for lanes >= 4
    if ((lane & 3) == 0) {
        const float inflow = (lane == 0) ? ((pb < 0) ? pre : pq) : prev;
        __builtin_nontemporal_store(Hb + inflow - of, &H_new[bucket]);
    }

    // ---- network outflow over last layer (block-uniform branch) ----
    if (t >= (NB - BPL) * 4) {
        float part = of;                 // uniform per 4-lane group
        part += __shfl_xor(part, 4);
        part += __shfl_xor(part, 8);
        part += __shfl_xor(part, 16);
        part += __shfl_xor(part, 32);    // all lanes: wave total (16 buckets)

        __shared__ float wsum[4];
        if (lane == 0) wsum[threadIdx.x >> 6] = part;
        __syncthreads();
        if (threadIdx.x == 0) {
            atomicAdd(net_out, (wsum[0] + wsum[1]) + (wsum[2] + wsum[3]));
        }
    }
}

extern "C" void kernel_launch(void* const* d_in, const int* in_sizes, int n_in,
                              void* d_out, int out_size, void* d_ws, size_t ws_size,
                              hipStream_t stream) {
    const float* H      = (const float*)d_in[0];   // [NB]
    const float* S      = (const float*)d_in[1];   // [NB, NS, 2]
    const float* theta  = (const float*)d_in[2];   // [NB*NS]
    const float* precip = (const float*)d_in[3];   // scalar

    float* out     = (float*)d_out;
    float* H_new   = out;                               // [NB]
    float* s_q     = out + NB;                          // [NB, NS]
    float* net_out = out + NB + (size_t)NB * NS;        // scalar

    // scalar slot is poisoned 0xAA each run -> zero it (capture-safe memset)
    hipMemsetAsync(net_out, 0, sizeof(float), stream);

    fused_kernel<<<(NB * 4) / 256, 256, 0, stream>>>(
        H, S, theta, precip, s_q, H_new, net_out);
}